// Round 1
// 222.534 us; speedup vs baseline: 1.0033x; 1.0033x over previous
//
#include <hip/hip_runtime.h>
#include <math.h>

#define NB    16        // batch
#define NC    25        // channels
#define HW    65536     // 256*256
#define CHW   (NC * HW)
#define EPSF  1e-8f
#define TPB   256       // 4 waves
#define BPI   64        // blocks per image; slab = 1024 px
#define SLAB  1024
#define WPX   256       // pixels per wave (64 lanes x 4)
#define GR    5         // channels per staged group
#define NGRP  5         // 25 channels = 5 groups

union F4 { float4 v; float a[4]; };

typedef const float __attribute__((address_space(1)))* gp_t;  // global
typedef float       __attribute__((address_space(3)))* lp_t;  // LDS

// counted vmcnt wait: never drain to 0 in the pipeline (T4 pattern)
#define WAITV(N) asm volatile("s_waitcnt vmcnt(" #N ")" ::: "memory")

__device__ __forceinline__ float wave_reduce(float v) {
#pragma unroll
    for (int o = 32; o > 0; o >>= 1) v += __shfl_down(v, o, 64);
    return v;
}

// R8: per-wave private pipeline, NO __syncthreads in the main loop.
// R7's premise failed: LDS_Block_Size=82432 -> 2x82432 > 160KiB -> only ONE
// block/CU (Occupancy 9.7% ~= one 4-wave block), and each __syncthreads
// drained vmcnt(0), waiting for the prefetched group too -> fully serial
// stage->drain->consume, 2.7 TB/s effective, latency-bound.
// Waves never share data (pure elementwise), so each wave gets a private
// triple-buffered LDS region and tracks its own global_load_lds completions
// with counted s_waitcnt vmcnt(N). Steady state 20-30 outstanding 1KB loads
// per wave (~100KB/CU in flight vs ~9KB needed for 6.3 TB/s).
__global__ __launch_bounds__(TPB) void yolo_main(const float* __restrict__ outputs,
                                                 const float* __restrict__ labels,
                                                 float* __restrict__ acc) {
    // [wave][buf][stream: 2*ci+{0=out,1=lab}][pixel] -- 120 KB, 1 block/CU
    __shared__ float lds[4][3][2 * GR][WPX];

    const int b    = blockIdx.x / BPI;
    const int slab = blockIdx.x % BPI;
    const size_t base = (size_t)b * CHW + (size_t)slab * SLAB;
    const int wv   = threadIdx.x >> 6;       // wave id 0..3 (uniform per wave)
    const int lane = threadIdx.x & 63;
    const int l4   = lane * 4;               // consume offset (floats)

    // per-lane global pointers for this wave's private 1KB slab of each stream
    const float* og = outputs + base + wv * WPX + l4;
    const float* lg = labels  + base + wv * WPX + l4;

    float y0[4], vmax[4], vout[4];
    float obj = 0.f, szs = 0.f, offs = 0.f, cls = 0.f;
    float tp = 0.f, fp = 0.f, fn = 0.f;
#pragma unroll
    for (int i = 0; i < 4; ++i) { vmax[i] = -1.0f; vout[i] = 0.0f; }

    // stage group g (channels g*GR .. g*GR+4) into this wave's buffer bf:
    // 10 async 16B/lane loads (1KB each), LDS base wave-uniform.
    auto stage = [&](int g, int bf) {
#pragma unroll
        for (int ci = 0; ci < GR; ++ci) {
            const size_t choff = (size_t)(g * GR + ci) * HW;
            __builtin_amdgcn_global_load_lds((gp_t)(og + choff),
                                             (lp_t)&lds[wv][bf][2 * ci + 0][0], 16, 0, 0);
            __builtin_amdgcn_global_load_lds((gp_t)(lg + choff),
                                             (lp_t)&lds[wv][bf][2 * ci + 1][0], 16, 0, 0);
        }
    };

    // channels 5..24: argmax(labels) carrying outputs.
    // ascending channel order + strict > = argmax first-index tie-break
    auto consume_cls = [&](int bf) {
#pragma unroll
        for (int ci = 0; ci < GR; ++ci) {
            F4 o, l;
            o.v = *(const float4*)&lds[wv][bf][2 * ci + 0][l4];
            l.v = *(const float4*)&lds[wv][bf][2 * ci + 1][l4];
#pragma unroll
            for (int i = 0; i < 4; ++i) {
                if (l.a[i] > vmax[i]) { vmax[i] = l.a[i]; vout[i] = o.a[i]; }
            }
        }
    };

    // pipeline prologue: 2 groups in flight before first wait, 3 before use
    stage(0, 0);
    stage(1, 1);

    // ---- group 0 (channels 0..4): BCE + F1 + size/offset L1
    stage(2, 2);          // 30 loads issued
    WAITV(20);            // group 0's 10 landed
    {
        F4 x, y;
        x.v = *(const float4*)&lds[wv][0][0][l4];
        y.v = *(const float4*)&lds[wv][0][1][l4];
#pragma unroll
        for (int i = 0; i < 4; ++i) {
            float xv = x.a[i], yv = y.a[i];
            float xc = fminf(fmaxf(xv,        EPSF), 1.0f - EPSF);
            float x1 = fminf(fmaxf(1.0f - xv, EPSF), 1.0f - EPSF);
            obj += -yv * (1.0f - xc) * __logf(xc)
                   - (1.0f - yv) * (1.0f - x1) * __logf(x1);
            float p  = (xv > 0.5f) ? 1.f : 0.f;
            float yt = (yv > 0.5f) ? 1.f : 0.f;
            tp += p * yt;
            fp += p * (1.f - yt);
            fn += (1.f - p) * yt;
            y0[i] = yv;
        }
#pragma unroll
        for (int ci = 1; ci <= 4; ++ci) {
            F4 o, l;
            o.v = *(const float4*)&lds[wv][0][2 * ci + 0][l4];
            l.v = *(const float4*)&lds[wv][0][2 * ci + 1][l4];
            float s = 0.f;
#pragma unroll
            for (int i = 0; i < 4; ++i) s += y0[i] * fabsf(o.a[i] - l.a[i]);
            if (ci <= 2) szs += s; else offs += s;
        }
    }

    // ---- group 1 (buf 1); refill buf 0 (group 0 consumed) with group 3
    stage(3, 0);
    WAITV(20);
    consume_cls(1);

    // ---- group 2 (buf 2); refill buf 1 with group 4
    stage(4, 1);
    WAITV(20);
    consume_cls(2);

    // ---- group 3 (buf 0); nothing left to stage
    WAITV(10);
    consume_cls(0);

    // ---- group 4 (buf 1)
    WAITV(0);
    consume_cls(1);

#pragma unroll
    for (int i = 0; i < 4; ++i) cls += y0[i] * (-vout[i]);

    // ---- block reduction: 7 values (single barrier, pipelines already done)
    obj  = wave_reduce(obj);
    szs  = wave_reduce(szs);
    offs = wave_reduce(offs);
    cls  = wave_reduce(cls);
    tp   = wave_reduce(tp);
    fp   = wave_reduce(fp);
    fn   = wave_reduce(fn);

    __shared__ float sm[TPB / 64][7];
    if (lane == 0) {
        sm[wv][0] = obj;  sm[wv][1] = szs; sm[wv][2] = offs;
        sm[wv][3] = cls;  sm[wv][4] = tp;  sm[wv][5] = fp;  sm[wv][6] = fn;
    }
    __syncthreads();
    if (threadIdx.x < 7) {
        float s = 0.f;
#pragma unroll
        for (int w = 0; w < TPB / 64; ++w) s += sm[w][threadIdx.x];
        if (threadIdx.x < 4) atomicAdd(&acc[threadIdx.x], s);
        else                 atomicAdd(&acc[4 + 3 * b + (threadIdx.x - 4)], s);
    }
}

__global__ void yolo_fin(const float* __restrict__ acc, float* __restrict__ out) {
    if (threadIdx.x == 0) {
        float obj = acc[0];
        float sz  = 0.1f * acc[1];
        float off = 0.1f * acc[2];
        float cls = acc[3];
        float f1 = 0.f;
        for (int b = 0; b < NB; ++b) {
            float tp = acc[4 + 3 * b], fp = acc[5 + 3 * b], fn = acc[6 + 3 * b];
            float den = 2.f * tp + fp + fn;
            f1 += (den > 0.f) ? (2.f * tp) / fmaxf(den, 1.f) : 0.f;
        }
        f1 *= (1.0f / NB);
        out[0] = obj + sz + off + cls;
        out[1] = f1;
        out[2] = obj;
        out[3] = sz;
        out[4] = off;
        out[5] = cls;
    }
}

extern "C" void kernel_launch(void* const* d_in, const int* in_sizes, int n_in,
                              void* d_out, int out_size, void* d_ws, size_t ws_size,
                              hipStream_t stream) {
    const float* outputs = (const float*)d_in[0];
    const float* labels  = (const float*)d_in[1];
    float* acc = (float*)d_ws;   // [0]obj [1]szs [2]offs [3]cls [4+3b..] tp,fp,fn

    hipMemsetAsync(acc, 0, (4 + 3 * NB) * sizeof(float), stream);
    yolo_main<<<NB * BPI, TPB, 0, stream>>>(outputs, labels, acc);
    yolo_fin<<<1, 64, 0, stream>>>(acc, (float*)d_out);
}